// Round 6
// baseline (5818.145 us; speedup 1.0000x reference)
//
#include <hip/hip_runtime.h>
#include <hip/hip_bf16.h>
#include <stdint.h>

#define B_   64
#define T_   1024
#define D_   300
#define H_   512
#define G4H  2048
#define KP   320   // K padded to multiple of 32 for the x-proj GEMM

typedef __attribute__((ext_vector_type(8))) short short8;   // 8 x bf16 (4 VGPRs)
typedef __attribute__((ext_vector_type(4))) short sh4;      // 4 x bf16 (2 VGPRs)
typedef __attribute__((ext_vector_type(4))) float f32x4;
typedef unsigned long long ull;

__device__ __forceinline__ unsigned short f2bf(float v) {
    __hip_bfloat16 h = __float2bfloat16(v);
    return *reinterpret_cast<unsigned short*>(&h);
}
__device__ __forceinline__ float bf2f(unsigned u) {      // low 16 bits = bf16
    return __uint_as_float(u << 16);
}
__device__ __forceinline__ float sigm(float x) { return 1.f / (1.f + __expf(-x)); }
__device__ __forceinline__ float tanhfast(float x) {
    float e = __expf(2.f * x);            // inf-safe: x>>0 -> 1, x<<0 -> -1
    return 1.f - 2.f / (e + 1.f);
}

// LDS-only barrier: does NOT drain vmcnt (unlike __syncthreads, which emits
// s_waitcnt vmcnt(0) before s_barrier and would serialize fire-and-forget
// stores + in-flight polls/prefetches into the critical path).
__device__ __forceinline__ void bar_lds() {
    asm volatile("s_waitcnt lgkmcnt(0)" ::: "memory");
    __builtin_amdgcn_s_barrier();
    asm volatile("" ::: "memory");
}

#define ASYNC16(g, l)                                                        \
    __builtin_amdgcn_global_load_lds(                                        \
        (const __attribute__((address_space(1))) void*)(g),                  \
        (__attribute__((address_space(3))) void*)(l), 16, 0, 0)

// ---------------------------------------------------------------------------
// Kernel 1: essays fp32 [65536][300] -> bf16 [65536][320] (zero-padded K)
// ---------------------------------------------------------------------------
__global__ void cvt_essays(const float* __restrict__ es, unsigned short* __restrict__ Ab) {
    unsigned i = blockIdx.x * 256u + threadIdx.x;       // exactly 65536*320 threads
    unsigned row = i / KP;
    unsigned col = i - row * KP;
    float v = (col < D_) ? es[(size_t)row * D_ + col] : 0.f;
    Ab[i] = f2bf(v);
}

// ---------------------------------------------------------------------------
// Kernel 2: Wx transpose+pad -> bf16 WxT[2048][320]
// ---------------------------------------------------------------------------
__global__ void cvt_misc(const float* __restrict__ Wl, unsigned short* __restrict__ Bt) {
    unsigned i = blockIdx.x * 256u + threadIdx.x;       // exactly 2048*320 threads
    unsigned n = i / KP, k = i - n * KP;
    float v = (k < D_) ? Wl[(size_t)k * G4H + n] : 0.f;   // Wx rows 0..299
    Bt[i] = f2bf(v);
}

// ---------------------------------------------------------------------------
// Kernel 2b: Wh transpose -> bf16 WhTg[2048][512] (coalesced block staging)
// ---------------------------------------------------------------------------
__global__ void cvt_wh(const float* __restrict__ Wl, unsigned short* __restrict__ WhTg) {
    unsigned i = blockIdx.x * 256u + threadIdx.x;       // 2048*512 threads
    unsigned gc = i & 2047u, k = i >> 11;
    WhTg[(size_t)gc * 512 + k] = f2bf(Wl[(size_t)(300 + k) * G4H + gc]);
}

// ---------------------------------------------------------------------------
// Kernel 2c: poison both hfp step-buffers with tag-2 dwords (0xAAAAAAAA) so a
// consumer's first read (want tag 0) can never accept stale pre-LSTM bytes.
// Must run AFTER gemm_xp (hfp overlaps the Ab region).
// ---------------------------------------------------------------------------
__global__ void poison_hfp(unsigned* __restrict__ hfp) {
    hfp[blockIdx.x * 256u + threadIdx.x] = 0xAAAAAAAAu;   // 256 blocks -> 64K dwords
}

// ---------------------------------------------------------------------------
// Kernel 3: x_proj GEMM -> xpr in the recurrence layout:
//   per (t, g=batch-group, sl=j-slice of 16): 256 thread-slots x 4 bf16
//   idx = (((t*4+g)*32+sl)*256 + tid)*4 + gate
// where the lstm thread tid = w*64 + q*16 + ln owns
//   b = q*4 + (ln&3),  jl = w*4 + (ln>>2)
// so each lstm thread reads ONE 8B chunk per step (its 4 gate pre-activations).
// ---------------------------------------------------------------------------
__global__ __launch_bounds__(256) void gemm_xp(
    const unsigned short* __restrict__ Ab,   // [65536][320] bf16
    const unsigned short* __restrict__ Bt,   // [2048][320]  bf16 (WxT)
    const float* __restrict__ bias,          // [2048]
    unsigned short* __restrict__ xpr)        // [65536*2048] bf16, permuted
{
    __shared__ __align__(16) unsigned short Al[128 * 32];
    __shared__ __align__(16) unsigned short Bl[128 * 32];
    const int tid = threadIdx.x;
    const int w = tid >> 6, lane = tid & 63;
    const int ln = lane & 15, q = lane >> 4;
    const int bx = blockIdx.x;
    const int m0 = (bx >> 4) * 128;          // consecutive blocks share the A tile
    const int n0 = (bx & 15) * 128;
    const int wr = w >> 1, wc = w & 1;

    f32x4 acc[4][4];
#pragma unroll
    for (int i = 0; i < 4; i++)
#pragma unroll
        for (int j = 0; j < 4; j++) acc[i][j] = (f32x4){0.f, 0.f, 0.f, 0.f};

    for (int k0 = 0; k0 < KP; k0 += 32) {
#pragma unroll
        for (int it = 0; it < 2; ++it) {
            int s = it * 4 + w;              // wave-uniform segment id
            int c = s * 64 + lane;           // 16B chunk id, 0..511
            int r = c >> 2;                  // tile row 0..127
            int ko = (c & 3) * 8;            // k offset in elements
            ASYNC16(Ab + (size_t)(m0 + r) * KP + k0 + ko, &Al[s * 512]);
            ASYNC16(Bt + (size_t)(n0 + r) * KP + k0 + ko, &Bl[s * 512]);
        }
        __syncthreads();
        short8 af[4], bf[4];
#pragma unroll
        for (int mt = 0; mt < 4; ++mt)
            af[mt] = *(const short8*)&Al[(wr * 64 + mt * 16 + ln) * 32 + q * 8];
#pragma unroll
        for (int nt = 0; nt < 4; ++nt)
            bf[nt] = *(const short8*)&Bl[(wc * 64 + nt * 16 + ln) * 32 + q * 8];
#pragma unroll
        for (int mt = 0; mt < 4; ++mt)
#pragma unroll
            for (int nt = 0; nt < 4; ++nt)
                acc[mt][nt] = __builtin_amdgcn_mfma_f32_16x16x32_bf16(af[mt], bf[nt], acc[mt][nt], 0, 0, 0);
        __syncthreads();
    }
#pragma unroll
    for (int mt = 0; mt < 4; ++mt) {
#pragma unroll
        for (int nt = 0; nt < 4; ++nt) {
            int col = n0 + wc * 64 + nt * 16 + ln;
            int gate = col >> 9, j9 = col & 511;
            int sl = j9 >> 4, jl = j9 & 15;
            float bb = bias[col];
#pragma unroll
            for (int r = 0; r < 4; ++r) {
                int row = m0 + wr * 64 + mt * 16 + q * 4 + r;   // C/D: col=lane&15, row=quad*4+reg
                int t = row & 1023, bglob = row >> 10;
                int g = bglob >> 4, b = bglob & 15;
                int tidl = (jl >> 2) * 64 + (b >> 2) * 16 + (jl & 3) * 4 + (b & 3);
                size_t idx = ((((size_t)t * 4 + g) * 32 + sl) * 256 + tidl) * 4 + gate;
                xpr[idx] = f2bf(acc[mt][nt][r] + bb);
            }
        }
    }
}

// ---------------------------------------------------------------------------
// Kernel 4: persistent LSTM recurrence. 128 blocks = 4 groups x 32 j-slices
// (16 j's each), 256 threads, one (b,j) per thread — round-4's exact design
// with ONE delta: amdgpu_waves_per_eu(1,1).
// Round-4 counters proved scratch spill on the chain (WRITE_SIZE +131072 KB
// == exactly 4B/thread/step; VGPR_Count=84 == the 6-waves/EU allocation
// point). Physical occupancy is 1 wave/EU (128 blocks / 256 CUs), so cap the
// allocator's occupancy target at 1 wave/EU -> up to 512 VGPRs -> bv[16] +
// v[16] stay resident. NOTE: __launch_bounds__ has only the flat-workgroup-
// size arg here so waves-per-eu metadata comes from exactly one attribute.
// Design (carried from round 4, harness-verified):
//   - Wh slice in REGISTERS (bv[16] = 64 VGPRs). LDS = hl only (16.6 KB).
//   - Gate-interleaved cols + 4-lane shfl 4x4 transpose: no gbuf round-trip.
//   - bar_lds (lgkmcnt-only s_barrier): stores/polls/prefetch never drained.
//   - Polls for h(t+1) issued BEFORE the h(t+1) store (issue-order vmcnt:
//     the next-step first check never waits on our own store's ack).
//   - Self-slice short-circuit: own 16x16 h-tile written directly to LDS;
//     own poll chunks skipped (polled chunks are all FOREIGN).
// Transport protocol unchanged (proven): fp32 h, 2-bit step tag mod 4 in
// mantissa LSBs, [2][64][512] buffers, per-dword tag retry, skew<=1,
// poison tag 2 never matches first-read want=0.
// ---------------------------------------------------------------------------
__global__ __launch_bounds__(256) __attribute__((amdgpu_waves_per_eu(1, 1)))
void lstm_rec(
    const unsigned short* __restrict__ WhTg, // [2048][512] bf16 (pre-transposed Wh)
    const unsigned short* __restrict__ xpr,  // permuted x_proj (see gemm_xp)
    unsigned* __restrict__ hfp,              // [2][64][512] fp32 h, tag in low bits
    float* __restrict__ hmean)               // [64][512] fp32
{
    __shared__ __align__(16) unsigned short hl[16 * 520];    // [b][j(512)] pad 520

    const int tid = threadIdx.x;
    const int g   = blockIdx.x >> 5;         // batch group 0..3
    const int sl  = blockIdx.x & 31;         // j-slice 0..31 (16 j's)
    const int w = tid >> 6, lane = tid & 63, ln = lane & 15, q = lane >> 4;
    const int m = ln & 3;
    const int b  = q * 4 + m;                // this thread's batch row (post-transpose)
    const int jl = w * 4 + (ln >> 2);        // this thread's local j
    const bool skip = (tid >= 8 * sl) && (tid < 8 * sl + 8);  // own j-pair chunks

    // ---- one-time: this wave's 16 Wh columns (gate-interleaved) -> registers
    // lane ln covers col gc = gate*512 + sl*16 + jsub with gate=ln&3, jsub=w*4+(ln>>2)
    short8 bv[16];
    {
        int gc = (ln & 3) * 512 + sl * 16 + w * 4 + (ln >> 2);
        const unsigned short* wp = WhTg + (size_t)gc * 512 + q * 8;
#pragma unroll
        for (int kk = 0; kk < 16; ++kk)
            bv[kk] = *(const short8*)(wp + kk * 32);
    }
    // ---- h(0) = 0
    for (int i2 = tid; i2 < 4160; i2 += 256) ((unsigned*)hl)[i2] = 0u;
    __syncthreads();                          // one-time full barrier is fine

    float cst = 0.f, hsum = 0.f;
    sh4 xc = *(const sh4*)&xpr[((size_t)(g * 32 + sl) * 256 + tid) * 4];
    sh4 xn;
    ull v[16];                                // in-flight poll registers

    for (int t = 0; t < T_; ++t) {
        // ---- xp(t+1) prefetch (one 8B load; consumed at end of this step)
        if (t + 1 < T_)
            xn = *(const sh4*)&xpr[((((size_t)(t + 1) * 4 + g) * 32 + sl) * 256 + tid) * 4];

        // ---- consume h_g(t): check pre-issued polls, retry bad chunks.
        // Polls were issued BEFORE last step's store -> this wait is pure load
        // latency. Own-slice threads (skip) have nothing to poll: their data
        // was written into hl locally at the end of step t-1.
        if (t > 0 && !skip) {
            const ull* src = (const ull*)(hfp + (size_t)(t & 1) * 32768 + g * 8192);
            const unsigned want = (unsigned)((t >> 1) & 3);
            while (true) {
                unsigned bad = 0u;
#pragma unroll
                for (int i = 0; i < 16; ++i) {
                    unsigned lo = (unsigned)v[i], hi = (unsigned)(v[i] >> 32);
                    bad |= ((((lo & 3u) ^ want) | ((hi & 3u) ^ want)) != 0u) ? (1u << i) : 0u;
                }
                if (!bad) break;
#pragma unroll
                for (int i = 0; i < 16; ++i)
                    if (bad & (1u << i))
                        v[i] = __hip_atomic_load(src + tid + (i << 8),
                                                 __ATOMIC_RELAXED, __HIP_MEMORY_SCOPE_AGENT);
            }
            // decode fp32(tagged) -> bf16 pair -> hl; thread owns j-pair {2tid,2tid+1}
#pragma unroll
            for (int i = 0; i < 16; ++i) {
                unsigned uu = (unsigned)f2bf(__uint_as_float((unsigned)v[i]))
                            | ((unsigned)f2bf(__uint_as_float((unsigned)(v[i] >> 32))) << 16);
                *(unsigned*)((char*)hl + i * 1040 + tid * 4) = uu;
            }
        }
        bar_lds();                            // bar1: RAW on hl (no vmcnt drain)

        // ---- gates = h_g(t) @ Wh-slice : 2 K-half chains (8-deep each)
        f32x4 a0 = (f32x4){0.f,0.f,0.f,0.f};
        f32x4 b0 = (f32x4){0.f,0.f,0.f,0.f};
#pragma unroll
        for (int kk = 0; kk < 8; ++kk) {
            short8 av = *(const short8*)&hl[ln * 520 + kk * 32 + q * 8];
            a0 = __builtin_amdgcn_mfma_f32_16x16x32_bf16(av, bv[kk], a0, 0, 0, 0);
        }
#pragma unroll
        for (int kk = 8; kk < 16; ++kk) {
            short8 av = *(const short8*)&hl[ln * 520 + kk * 32 + q * 8];
            b0 = __builtin_amdgcn_mfma_f32_16x16x32_bf16(av, bv[kk], b0, 0, 0, 0);
        }
        bar_lds();                            // bar2: WAR on hl (reads retired)

        // ---- 4x4 transpose in 4-lane groups, elementwise, write-local, store
        float x0 = a0[0] + b0[0], x1 = a0[1] + b0[1];
        float x2 = a0[2] + b0[2], x3 = a0[3] + b0[3];
        float s0 = (m & 1) ? x0 : x1, s1 = (m & 1) ? x2 : x3;
        s0 = __shfl_xor(s0, 1); s1 = __shfl_xor(s1, 1);
        if (m & 1) { x0 = s0; x2 = s1; } else { x1 = s0; x3 = s1; }
        float u0 = (m & 2) ? x0 : x2, u1 = (m & 2) ? x1 : x3;
        u0 = __shfl_xor(u0, 2); u1 = __shfl_xor(u1, 2);
        if (m & 2) { x0 = u0; x1 = u1; } else { x2 = u0; x3 = u1; }
        // x0..x3 = i,j,f,o (Wh part) for (b, jl)
        float ai  = x0 + bf2f((unsigned)(unsigned short)xc[0]);
        float aj  = x1 + bf2f((unsigned)(unsigned short)xc[1]);
        float af_ = x2 + bf2f((unsigned)(unsigned short)xc[2]);
        float ao  = x3 + bf2f((unsigned)(unsigned short)xc[3]);
        float si = sigm(ai), tj = tanhfast(aj);
        float sf = sigm(af_ + 1.0f), so = sigm(ao);
        cst = cst * sf + si * tj;
        float h = tanhfast(cst) * so;
        hsum += h;
        xc = xn;

        // own h(t+1) -> LDS directly (hl dead after bar2; own slice never
        // round-trips through global on the consume side)
        hl[b * 520 + sl * 16 + jl] = f2bf(h);

        // ---- pre-issue polls for h_g(t+1) BEFORE the store (issue-order vmcnt:
        // next-step check then never waits on our own store's ack)
        if (t + 1 < T_ && !skip) {
            const ull* src2 = (const ull*)(hfp + (size_t)((t + 1) & 1) * 32768 + g * 8192);
#pragma unroll
            for (int i = 0; i < 16; ++i)
                v[i] = __hip_atomic_load(src2 + tid + (i << 8),
                                         __ATOMIC_RELAXED, __HIP_MEMORY_SCOPE_AGENT);
        }

        // ---- fire-and-forget tagged store of h(t+1) for foreign consumers
        unsigned hb = (__float_as_uint(h) & ~3u) | (unsigned)(((t + 1) >> 1) & 3);
        __hip_atomic_store(hfp + (size_t)((t + 1) & 1) * 32768 + (g * 16 + b) * 512 + sl * 16 + jl,
                           hb, __ATOMIC_RELAXED, __HIP_MEMORY_SCOPE_AGENT);
    }
    hmean[(size_t)(g * 16 + b) * 512 + sl * 16 + jl] = hsum * (1.f / 1024.f);
}

// ---------------------------------------------------------------------------
// Kernel 5: preds = sigmoid(hmean @ W_dense + b_dense), one wave per batch row
// ---------------------------------------------------------------------------
__global__ void dense_out(const float* __restrict__ hmean, const float* __restrict__ Wd,
                          const float* __restrict__ bd, float* __restrict__ out) {
    int bb = blockIdx.x;
    int lane = threadIdx.x;
    float p = 0.f;
    for (int e = lane; e < H_; e += 64) p += hmean[(size_t)bb * H_ + e] * Wd[e];
#pragma unroll
    for (int off = 32; off; off >>= 1) p += __shfl_down(p, off);
    if (lane == 0) out[bb] = 1.f / (1.f + __expf(-(p + bd[0])));
}

// ---------------------------------------------------------------------------
extern "C" void kernel_launch(void* const* d_in, const int* in_sizes, int n_in,
                              void* d_out, int out_size, void* d_ws, size_t ws_size,
                              hipStream_t stream) {
    const float* essays  = (const float*)d_in[0];
    const float* W_lstm  = (const float*)d_in[1];
    const float* b_lstm  = (const float*)d_in[2];
    const float* W_dense = (const float*)d_in[3];
    const float* b_dense = (const float*)d_in[4];
    float* out = (float*)d_out;

    char* ws = (char*)d_ws;
    unsigned short* xp   = (unsigned short*)(ws);                   // 256 MB (permuted)
    unsigned short* Ab   = (unsigned short*)(ws + 268435456ull);    // 40 MB (dead after gemm_xp)
    unsigned short* Bt   = (unsigned short*)(ws + 310378496ull);    // 1.25 MB
    unsigned short* WhTg = (unsigned short*)(ws + 311689216ull);    // 2 MB
    // hfp/hm overlap the Ab region (Ab dead once gemm_xp completes)
    unsigned*       hfp  = (unsigned*)(ws + 268435456ull);          // 256 KB
    float*          hm   = (float*)(ws + 268435456ull + 262144ull); // 128 KB

    hipLaunchKernelGGL(cvt_essays, dim3(81920), dim3(256), 0, stream, essays, Ab);
    hipLaunchKernelGGL(cvt_misc,   dim3(2560),  dim3(256), 0, stream, W_lstm, Bt);
    hipLaunchKernelGGL(cvt_wh,     dim3(4096),  dim3(256), 0, stream, W_lstm, WhTg);
    hipLaunchKernelGGL(gemm_xp,    dim3(8192),  dim3(256), 0, stream, Ab, Bt, b_lstm, xp);
    hipLaunchKernelGGL(poison_hfp, dim3(256),   dim3(256), 0, stream, hfp);
    hipLaunchKernelGGL(lstm_rec,   dim3(128),   dim3(256), 0, stream, WhTg, xp, hfp, hm);
    hipLaunchKernelGGL(dense_out,  dim3(64),    dim3(64),  0, stream, hm, W_dense, b_dense, out);
}

// Round 7
// 3593.492 us; speedup vs baseline: 1.6191x; 1.6191x over previous
//
#include <hip/hip_runtime.h>
#include <hip/hip_bf16.h>
#include <stdint.h>

#define B_   64
#define T_   1024
#define D_   300
#define H_   512
#define G4H  2048
#define KP   320   // K padded to multiple of 32 for the x-proj GEMM

typedef __attribute__((ext_vector_type(8))) short short8;   // 8 x bf16 (4 VGPRs)
typedef __attribute__((ext_vector_type(4))) float f32x4;
typedef unsigned long long ull;

__device__ __forceinline__ unsigned short f2bf(float v) {
    __hip_bfloat16 h = __float2bfloat16(v);
    return *reinterpret_cast<unsigned short*>(&h);
}
__device__ __forceinline__ float bf2f(unsigned u) {      // low 16 bits = bf16
    return __uint_as_float(u << 16);
}
__device__ __forceinline__ float sigm(float x) { return 1.f / (1.f + __expf(-x)); }
__device__ __forceinline__ float tanhfast(float x) {
    float e = __expf(2.f * x);            // inf-safe: x>>0 -> 1, x<<0 -> -1
    return 1.f - 2.f / (e + 1.f);
}

// LDS-only barrier: does NOT drain vmcnt (unlike __syncthreads, which emits
// s_waitcnt vmcnt(0) before s_barrier). Keeps the xp prefetch and the
// fire-and-forget h store out of the serial per-step chain. Construct
// HW-validated (rounds 2/4/6 all passed with identical barrier semantics).
__device__ __forceinline__ void bar_lds() {
    asm volatile("s_waitcnt lgkmcnt(0)" ::: "memory");
    __builtin_amdgcn_s_barrier();
    asm volatile("" ::: "memory");
}

#define ASYNC16(g, l)                                                        \
    __builtin_amdgcn_global_load_lds(                                        \
        (const __attribute__((address_space(1))) void*)(g),                  \
        (__attribute__((address_space(3))) void*)(l), 16, 0, 0)

// ---------------------------------------------------------------------------
// Kernel 1: essays fp32 [65536][300] -> bf16 [65536][320] (zero-padded K)
// ---------------------------------------------------------------------------
__global__ void cvt_essays(const float* __restrict__ es, unsigned short* __restrict__ Ab) {
    unsigned i = blockIdx.x * 256u + threadIdx.x;       // exactly 65536*320 threads
    unsigned row = i / KP;
    unsigned col = i - row * KP;
    float v = (col < D_) ? es[(size_t)row * D_ + col] : 0.f;
    Ab[i] = f2bf(v);
}

// ---------------------------------------------------------------------------
// Kernel 2: Wx transpose+pad -> bf16 WxT[2048][320]
// ---------------------------------------------------------------------------
__global__ void cvt_misc(const float* __restrict__ Wl, unsigned short* __restrict__ Bt) {
    unsigned i = blockIdx.x * 256u + threadIdx.x;       // exactly 2048*320 threads
    unsigned n = i / KP, k = i - n * KP;
    float v = (k < D_) ? Wl[(size_t)k * G4H + n] : 0.f;   // Wx rows 0..299
    Bt[i] = f2bf(v);
}

// ---------------------------------------------------------------------------
// Kernel 2b: Wh transpose -> bf16 WhTg[2048][512] (coalesced block staging)
// ---------------------------------------------------------------------------
__global__ void cvt_wh(const float* __restrict__ Wl, unsigned short* __restrict__ WhTg) {
    unsigned i = blockIdx.x * 256u + threadIdx.x;       // 2048*512 threads
    unsigned gc = i & 2047u, k = i >> 11;
    WhTg[(size_t)gc * 512 + k] = f2bf(Wl[(size_t)(300 + k) * G4H + gc]);
}

// ---------------------------------------------------------------------------
// Kernel 2c: poison both hfp step-buffers with tag-2 dwords (0xAAAAAAAA) so a
// consumer's first read (want tag 0) can never accept stale pre-LSTM bytes.
// Must run AFTER gemm_xp (hfp overlaps the Ab region).
// ---------------------------------------------------------------------------
__global__ void poison_hfp(unsigned* __restrict__ hfp) {
    hfp[blockIdx.x * 256u + threadIdx.x] = 0xAAAAAAAAu;   // 256 blocks -> 64K dwords
}

// ---------------------------------------------------------------------------
// Kernel 3: x_proj GEMM -> xpr in recurrence layout (round-0 layout):
//   xpr[((t*4+g)*32+slice)*1024 + b*64 + gate*16 + jj]   (bf16, bias added)
// where row = (g*16+b)*1024 + t, col = gate*512 + slice*16 + jj.
// Each lstm block-step then reads one contiguous 2 KB region.
// ---------------------------------------------------------------------------
__global__ __launch_bounds__(256) void gemm_xp(
    const unsigned short* __restrict__ Ab,   // [65536][320] bf16
    const unsigned short* __restrict__ Bt,   // [2048][320]  bf16 (WxT)
    const float* __restrict__ bias,          // [2048]
    unsigned short* __restrict__ xpr)        // [65536*2048] bf16, permuted
{
    __shared__ __align__(16) unsigned short Al[128 * 32];
    __shared__ __align__(16) unsigned short Bl[128 * 32];
    const int tid = threadIdx.x;
    const int w = tid >> 6, lane = tid & 63;
    const int ln = lane & 15, q = lane >> 4;
    const int bx = blockIdx.x;
    const int m0 = (bx >> 4) * 128;          // consecutive blocks share the A tile
    const int n0 = (bx & 15) * 128;
    const int wr = w >> 1, wc = w & 1;

    f32x4 acc[4][4];
#pragma unroll
    for (int i = 0; i < 4; i++)
#pragma unroll
        for (int j = 0; j < 4; j++) acc[i][j] = (f32x4){0.f, 0.f, 0.f, 0.f};

    for (int k0 = 0; k0 < KP; k0 += 32) {
#pragma unroll
        for (int it = 0; it < 2; ++it) {
            int s = it * 4 + w;              // wave-uniform segment id
            int c = s * 64 + lane;           // 16B chunk id, 0..511
            int r = c >> 2;                  // tile row 0..127
            int ko = (c & 3) * 8;            // k offset in elements
            ASYNC16(Ab + (size_t)(m0 + r) * KP + k0 + ko, &Al[s * 512]);
            ASYNC16(Bt + (size_t)(n0 + r) * KP + k0 + ko, &Bl[s * 512]);
        }
        __syncthreads();
        short8 af[4], bf[4];
#pragma unroll
        for (int mt = 0; mt < 4; ++mt)
            af[mt] = *(const short8*)&Al[(wr * 64 + mt * 16 + ln) * 32 + q * 8];
#pragma unroll
        for (int nt = 0; nt < 4; ++nt)
            bf[nt] = *(const short8*)&Bl[(wc * 64 + nt * 16 + ln) * 32 + q * 8];
#pragma unroll
        for (int mt = 0; mt < 4; ++mt)
#pragma unroll
            for (int nt = 0; nt < 4; ++nt)
                acc[mt][nt] = __builtin_amdgcn_mfma_f32_16x16x32_bf16(af[mt], bf[nt], acc[mt][nt], 0, 0, 0);
        __syncthreads();
    }
#pragma unroll
    for (int mt = 0; mt < 4; ++mt) {
#pragma unroll
        for (int nt = 0; nt < 4; ++nt) {
            int col = n0 + wc * 64 + nt * 16 + ln;
            int gate = col >> 9, r9 = col & 511;
            int slice = r9 >> 4, jj = r9 & 15;
            float bb = bias[col];
#pragma unroll
            for (int r = 0; r < 4; ++r) {
                int row = m0 + wr * 64 + mt * 16 + q * 4 + r;   // C/D: col=lane&15, row=quad*4+reg
                int t = row & 1023, bglob = row >> 10;
                int g = bglob >> 4, bloc = bglob & 15;
                size_t idx = ((((size_t)t * 4 + g) * 32 + slice) * 16 + bloc) * 64
                             + gate * 16 + jj;
                xpr[idx] = f2bf(acc[mt][nt][r] + bb);
            }
        }
    }
}

// ---------------------------------------------------------------------------
// Kernel 4: persistent LSTM recurrence — ROUND-0 BASE (proven 3252 us) with
// exactly two deltas, each mechanism-isolated:
//   DELTA 1: in-loop __syncthreads -> bar_lds (lgkmcnt-only). Round-0's
//     sync1/sync2 drained vmcnt(0): the xp prefetch and residual store acks
//     were serialized into the chain. The protocol tolerates in-flight vmem
//     across barriers (tag-validated polls, fire-and-forget stores).
//   DELTA 2: self-slice short-circuit. Own 16x16 h-tile written directly to
//     LDS after elementwise; the 8 threads whose poll chunks equal the own
//     slice (tid in [8*slice, 8*slice+8)) skip polling. Their chunks were
//     guaranteed stale on the first check (own store ~100ns old), forcing a
//     retry round every step.
// EVERYTHING else byte-identical to round-0: coalesced stores (wave = 4 rows
// x 64B full sectors — rounds 2-6 proved scattered 16B stores double
// WRITE_SIZE and slow visibility), at-consume polls, WhT staged in LDS,
// gbuf LDS transpose, 2-bit mod-4 tag protocol, skew<=1.
// ---------------------------------------------------------------------------
__global__ __launch_bounds__(256, 1) void lstm_rec(
    const unsigned short* __restrict__ WhTg, // [2048][512] bf16 (pre-transposed Wh)
    const unsigned short* __restrict__ xpr,  // permuted x_proj (see gemm_xp)
    unsigned* __restrict__ hfp,              // [2][64][512] fp32 h, tag in low bits
    float* __restrict__ hmean)               // [64][512] fp32
{
    __shared__ __align__(16) unsigned short WhT[64 * 520];   // [col][k], pad 520
    __shared__ __align__(16) unsigned short hl[16 * 520];    // [b][k], pad 520
    __shared__ float gbuf[4][16][17];                        // [gate][b][j], pad 17

    const int tid = threadIdx.x;
    const int bid = blockIdx.x;
    const int g     = bid >> 5;        // batch group 0..3
    const int slice = bid & 31;        // j-slice 0..31
    const int j0    = slice * 16;
    const int bg    = g * 16;
    const int wv = tid >> 6, lane = tid & 63, ln = lane & 15, q = lane >> 4;
    const bool skip = (tid >= 8 * slice) && (tid < 8 * slice + 8);  // own chunks

    // one-time: stage this block's 64 Wh columns (gate*16+j) from WhTg, coalesced
    for (int ch = tid; ch < 64 * 64; ch += 256) {            // 16B chunks
        int c = ch >> 6, off = (ch & 63) * 8;
        int gc = (c >> 4) * 512 + j0 + (c & 15);
        *(uint4*)&WhT[c * 520 + off] = *(const uint4*)&WhTg[(size_t)gc * 512 + off];
    }

    const int b = tid >> 4;            // local batch row 0..15
    const int j = tid & 15;            // local j
    const int rowoff = (bg + b) * 512;

    // h(0) = 0: zero the staged-h LDS
    {
        ull* hl8 = (ull*)hl;
#pragma unroll
        for (int i = 0; i < 16; ++i) {
            int c = tid + (i << 8);                          // ull chunk 0..4095
            int row = c >> 8, pair = c & 255;                // 256 ull per row
            hl8[(row * 1040 + pair * 8) >> 3] = 0ull;        // byte addr /8
        }
    }
    __syncthreads();                   // one-time full barrier (off the loop)

    float c_st = 0.f, hsum = 0.f;
    const unsigned short* xblk0 = xpr + ((size_t)g * 32 + slice) * 1024 + b * 64 + j;
    unsigned short xc0 = xblk0[0], xc1 = xblk0[16], xc2 = xblk0[32], xc3 = xblk0[48];
    unsigned short xn0 = xc0, xn1 = xc1, xn2 = xc2, xn3 = xc3;

    for (int t = 0; t < T_; ++t) {
        // issue xp(t+1) prefetch FIRST: latency hides under the poll below
        if (t + 1 < T_) {
            const unsigned short* xr = xblk0 + (size_t)(t + 1) * 131072;  // 4*32*1024
            xn0 = xr[0]; xn1 = xr[16]; xn2 = xr[32]; xn3 = xr[48];
        }
        if (t > 0 && !skip) {
            // poll h(t): coalesced 8B agent loads, per-dword tag check.
            // Own-slice threads (skip) have nothing to poll: their columns
            // were written into hl locally at the end of step t-1.
            const ull* src = (const ull*)(hfp + (size_t)(t & 1) * 32768 + bg * 512);
            const unsigned want = (unsigned)((t >> 1) & 3);
            ull v[16];
#pragma unroll
            for (int i = 0; i < 16; ++i)
                v[i] = __hip_atomic_load(src + tid + (i << 8),
                                         __ATOMIC_RELAXED, __HIP_MEMORY_SCOPE_AGENT);
            while (true) {
                unsigned bad = 0u;
#pragma unroll
                for (int i = 0; i < 16; ++i) {
                    unsigned lo = (unsigned)v[i], hi = (unsigned)(v[i] >> 32);
                    bad |= ((((lo & 3u) ^ want) | ((hi & 3u) ^ want)) != 0u) ? (1u << i) : 0u;
                }
                if (!bad) break;
#pragma unroll
                for (int i = 0; i < 16; ++i)
                    if (bad & (1u << i))
                        v[i] = __hip_atomic_load(src + tid + (i << 8),
                                                 __ATOMIC_RELAXED, __HIP_MEMORY_SCOPE_AGENT);
            }
            // decode: fp32 (tag bits negligible) -> bf16 pair -> LDS (2-way free)
#pragma unroll
            for (int i = 0; i < 16; ++i) {
                int c = tid + (i << 8);
                int row = c >> 8, pair = c & 255;
                unsigned u = (unsigned)f2bf(__uint_as_float((unsigned)v[i]))
                           | ((unsigned)f2bf(__uint_as_float((unsigned)(v[i] >> 32))) << 16);
                *(unsigned*)((char*)hl + row * 1040 + pair * 4) = u;
            }
        }
        bar_lds();                                           // bar1: RAW on hl

        // wave wv computes gate wv: 16(batch) x 16(j), K=512
        f32x4 acc = (f32x4){0.f, 0.f, 0.f, 0.f};
#pragma unroll
        for (int kk = 0; kk < 16; ++kk) {
            short8 av = *(const short8*)&hl[ln * 520 + kk * 32 + q * 8];
            short8 bv = *(const short8*)&WhT[(wv * 16 + ln) * 520 + kk * 32 + q * 8];
            acc = __builtin_amdgcn_mfma_f32_16x16x32_bf16(av, bv, acc, 0, 0, 0);
        }
#pragma unroll
        for (int r = 0; r < 4; ++r)
            gbuf[wv][q * 4 + r][ln] = acc[r];                // C/D: col=lane&15, row=quad*4+reg
        bar_lds();                                           // bar2: gbuf RAW + hl WAR

        // elementwise: thread (b, j)
        float ai  = gbuf[0][b][j] + bf2f((unsigned)xc0);
        float aj  = gbuf[1][b][j] + bf2f((unsigned)xc1);
        float af_ = gbuf[2][b][j] + bf2f((unsigned)xc2);
        float ao  = gbuf[3][b][j] + bf2f((unsigned)xc3);
        float si = sigm(ai), tj = tanhfast(aj);
        float sf = sigm(af_ + 1.0f), so = sigm(ao);
        c_st = c_st * sf + si * tj;
        float h = tanhfast(c_st) * so;
        hsum += h;
        xc0 = xn0; xc1 = xn1; xc2 = xn2; xc3 = xn3;

        // own h(t+1) -> LDS directly (hl region free after bar2): the own
        // slice never round-trips through global on the consume side
        hl[b * 520 + j0 + j] = f2bf(h);

        // fire-and-forget tagged store of h(t+1); no drain, no flag
        unsigned hb = (__float_as_uint(h) & ~3u) | (unsigned)(((t + 1) >> 1) & 3);
        __hip_atomic_store(hfp + (size_t)((t + 1) & 1) * 32768 + rowoff + j0 + j,
                           hb, __ATOMIC_RELAXED, __HIP_MEMORY_SCOPE_AGENT);
    }
    hmean[(size_t)rowoff + j0 + j] = hsum * (1.f / 1024.f);
}

// ---------------------------------------------------------------------------
// Kernel 5: preds = sigmoid(hmean @ W_dense + b_dense), one wave per batch row
// ---------------------------------------------------------------------------
__global__ void dense_out(const float* __restrict__ hmean, const float* __restrict__ Wd,
                          const float* __restrict__ bd, float* __restrict__ out) {
    int bb = blockIdx.x;
    int lane = threadIdx.x;
    float p = 0.f;
    for (int e = lane; e < H_; e += 64) p += hmean[(size_t)bb * H_ + e] * Wd[e];
#pragma unroll
    for (int off = 32; off; off >>= 1) p += __shfl_down(p, off);
    if (lane == 0) out[bb] = 1.f / (1.f + __expf(-(p + bd[0])));
}

// ---------------------------------------------------------------------------
extern "C" void kernel_launch(void* const* d_in, const int* in_sizes, int n_in,
                              void* d_out, int out_size, void* d_ws, size_t ws_size,
                              hipStream_t stream) {
    const float* essays  = (const float*)d_in[0];
    const float* W_lstm  = (const float*)d_in[1];
    const float* b_lstm  = (const float*)d_in[2];
    const float* W_dense = (const float*)d_in[3];
    const float* b_dense = (const float*)d_in[4];
    float* out = (float*)d_out;

    char* ws = (char*)d_ws;
    unsigned short* xp   = (unsigned short*)(ws);                   // 256 MB (permuted)
    unsigned short* Ab   = (unsigned short*)(ws + 268435456ull);    // 40 MB (dead after gemm_xp)
    unsigned short* Bt   = (unsigned short*)(ws + 310378496ull);    // 1.25 MB
    unsigned short* WhTg = (unsigned short*)(ws + 311689216ull);    // 2 MB
    // hfp/hm overlap the Ab region (Ab dead once gemm_xp completes)
    unsigned*       hfp  = (unsigned*)(ws + 268435456ull);          // 256 KB
    float*          hm   = (float*)(ws + 268435456ull + 262144ull); // 128 KB

    hipLaunchKernelGGL(cvt_essays, dim3(81920), dim3(256), 0, stream, essays, Ab);
    hipLaunchKernelGGL(cvt_misc,   dim3(2560),  dim3(256), 0, stream, W_lstm, Bt);
    hipLaunchKernelGGL(cvt_wh,     dim3(4096),  dim3(256), 0, stream, W_lstm, WhTg);
    hipLaunchKernelGGL(gemm_xp,    dim3(8192),  dim3(256), 0, stream, Ab, Bt, b_lstm, xp);
    hipLaunchKernelGGL(poison_hfp, dim3(256),   dim3(256), 0, stream, hfp);
    hipLaunchKernelGGL(lstm_rec,   dim3(128),   dim3(256), 0, stream, WhTg, xp, hfp, hm);
    hipLaunchKernelGGL(dense_out,  dim3(64),    dim3(64),  0, stream, hm, W_dense, b_dense, out);
}